// Round 7
// baseline (204.900 us; speedup 1.0000x reference)
//
#include <hip/hip_runtime.h>
#include <hip/hip_fp16.h>

#define N_NODES 50000
#define EMB 128
#define HID 64
#define NR 16
#define NC 16
#define NE 800000
#define J1 (NR*HID + HID)   /* 1088 = 17*64 */
#define J2 (NR*NC + NC)     /* 272  = 17*16 */
#define CAP 64              /* bucket capacity (deg~Poisson(16)) */
#define NXCD 8
#define DPX 6250            /* dst nodes per XCD slice */
#define ETILE 2048          /* edges per work-stealing tile */
#define NT ((NE + ETILE - 1) / ETILE)   /* 391 */

typedef _Float16 f16;
typedef __attribute__((ext_vector_type(8))) _Float16 f16x8;
typedef __attribute__((ext_vector_type(4))) _Float16 f16x4;
typedef __attribute__((ext_vector_type(4))) float f32x4;

// ---- fused pre-pass: [XCD-sliced scatter | cast emb->f16 | build Bt1/Bt2] ---
// Scatter: each block learns its XCD via HW_REG_XCC_ID; XCD k owns dst range
// [k*DPX, (k+1)*DPX). All XCDs stream all edges (work-stealing tiles via
// per-XCD counters) but write only their own cur/packed slice -> bucket lines
// stay in ONE XCD's L2 (no cross-XCD ping-pong), flushed once.
#define SCT_BLK 512
#define CAST_BLK 6250              /* 1,600,000 f16x4 groups */
#define BB_BLK 613
__global__ __launch_bounds__(256)
void k_pre(const float* __restrict__ emb, const float* __restrict__ W1,
           const float* __restrict__ root1, const float* __restrict__ W2,
           const float* __restrict__ root2, f16* __restrict__ embh,
           f16* __restrict__ Bt1, f16* __restrict__ Bt2,
           const int* __restrict__ ei, const int* __restrict__ et,
           int* __restrict__ cur, int* __restrict__ dctr,
           unsigned* __restrict__ packed) {
    __shared__ int s_t;
    int bx = blockIdx.x, tid = threadIdx.x;
    if (bx < SCT_BLK) {
        unsigned xcc;
        asm volatile("s_getreg_b32 %0, hwreg(HW_REG_XCC_ID)" : "=s"(xcc));
        int my = (int)(xcc & 7);
        int lo = my * DPX, hi = lo + DPX;
        for (;;) {
            if (tid == 0) s_t = atomicAdd(&dctr[my * 16], 1);
            __syncthreads();
            int t = s_t;
            __syncthreads();
            if (t >= NT) break;
            int base = t * ETILE;
#pragma unroll
            for (int k = 0; k < ETILE / 256; k++) {
                int e = base + (k << 8) + tid;
                if (e < NE) {
                    int d = ei[NE + e];                 // coalesced dst read
                    if (d >= lo && d < hi) {            // owned by my XCD
                        int s = ei[e], tt = et[e];
                        int pos = atomicAdd(&cur[d], 1);
                        if (pos < CAP)
                            packed[(size_t)d * CAP + pos] = (unsigned)(s * 17 + tt);
                    }
                }
            }
        }
    } else if (bx < SCT_BLK + CAST_BLK) {
        int i = (bx - SCT_BLK) * 256 + tid;
        if (i < N_NODES * EMB / 4) {
            float4 v = reinterpret_cast<const float4*>(emb)[i];
            f16x4 r = {(f16)v.x, (f16)v.y, (f16)v.z, (f16)v.w};
            reinterpret_cast<f16x4*>(embh)[i] = r;
        }
    } else {
        int idx = (bx - SCT_BLK - CAST_BLK) * 256 + tid;
        const int total1 = J1 * EMB;   // 139264
        const int total2 = J2 * HID;   // 17408
        if (idx < total1) {
            int j = idx / EMB, i = idx % EMB;
            float v = (j < NR*HID) ? W1[((size_t)(j >> 6) * EMB + i) * HID + (j & 63)]
                                   : root1[i * HID + (j - NR*HID)];
            Bt1[idx] = (f16)v;
        } else if (idx < total1 + total2) {
            int t = idx - total1;
            int j = t / HID, i = t % HID;
            float v = (j < NR*NC) ? W2[((size_t)(j >> 4) * HID + i) * NC + (j & 15)]
                                  : root2[i * NC + (j - NR*NC)];
            Bt2[t] = (f16)v;
        }
    }
}

// ---- MFMA GEMM: C[N,J] = A[N,K](f16) * Bt[J,K](f16)^T ----------------------
template<int K, typename OutT>
__global__ __launch_bounds__(512)
void k_mfma(const f16* __restrict__ A, const f16* __restrict__ Bt,
            OutT* __restrict__ C, int N, int J) {
    constexpr int KP = K + 8;
    __shared__ f16 As[128 * KP];
    __shared__ f16 Bs[128 * KP];
    int tid = threadIdx.x;
    int m0 = blockIdx.y * 128;
    int n0 = blockIdx.x * 128;

    constexpr int V = K / 8;
    for (int idx = tid; idx < 128 * V; idx += 512) {
        int r = idx / V, c = idx % V;
        f16x8 va = {}, vb = {};
        if (m0 + r < N) va = *reinterpret_cast<const f16x8*>(A + (size_t)(m0 + r) * K + c * 8);
        if (n0 + r < J) vb = *reinterpret_cast<const f16x8*>(Bt + (size_t)(n0 + r) * K + c * 8);
        *reinterpret_cast<f16x8*>(&As[r * KP + c * 8]) = va;
        *reinterpret_cast<f16x8*>(&Bs[r * KP + c * 8]) = vb;
    }
    __syncthreads();

    int w = tid >> 6, lane = tid & 63;
    int wr = (w >> 2) * 64, wc = (w & 3) * 32;
    int lr = lane & 15, lk = (lane >> 4) * 8;

    f32x4 acc[4][2];
#pragma unroll
    for (int mm = 0; mm < 4; mm++)
#pragma unroll
        for (int nn = 0; nn < 2; nn++) acc[mm][nn] = (f32x4){0.f, 0.f, 0.f, 0.f};

#pragma unroll
    for (int k0 = 0; k0 < K; k0 += 32) {
        f16x8 a[4], b[2];
#pragma unroll
        for (int mm = 0; mm < 4; mm++)
            a[mm] = *reinterpret_cast<const f16x8*>(&As[(wr + mm*16 + lr) * KP + k0 + lk]);
#pragma unroll
        for (int nn = 0; nn < 2; nn++)
            b[nn] = *reinterpret_cast<const f16x8*>(&Bs[(wc + nn*16 + lr) * KP + k0 + lk]);
#pragma unroll
        for (int mm = 0; mm < 4; mm++)
#pragma unroll
            for (int nn = 0; nn < 2; nn++)
                acc[mm][nn] = __builtin_amdgcn_mfma_f32_16x16x32_f16(a[mm], b[nn], acc[mm][nn], 0, 0, 0);
    }

    int g = lane >> 4;
#pragma unroll
    for (int mm = 0; mm < 4; mm++)
#pragma unroll
        for (int nn = 0; nn < 2; nn++) {
            int col = n0 + wc + nn*16 + lr;
            if (col < J) {
#pragma unroll
                for (int q = 0; q < 4; q++) {
                    int row = m0 + wr + mm*16 + g*4 + q;
                    if (row < N) C[(size_t)row * J + col] = (OutT)acc[mm][nn][q];
                }
            }
        }
}

// ---- fused layer-1 aggregation + finalize ----------------------------------
// wave/node; 4 edge-groups x 16 channel-quads; f16x4 loads; ballot counts.
__global__ __launch_bounds__(256)
void k_agg1f(const int* __restrict__ cur, const unsigned* __restrict__ packed,
             const f16* __restrict__ Y1, const float* __restrict__ b1,
             f16* __restrict__ X1h) {
    int n = (blockIdx.x * 256 + threadIdx.x) >> 6;
    if (n >= N_NODES) return;
    int lane = threadIdx.x & 63;
    int deg = cur[n]; if (deg > CAP) deg = CAP;
    unsigned my = packed[(size_t)n * CAP + lane];   // stale for lane>=deg, masked
    int tp = (int)(my % 17u);                       // 0..16 always
    float wreg = 0.f;
#pragma unroll
    for (int r = 0; r < 16; r++) {
        unsigned long long b = __ballot(lane < deg && tp == r);
        if (lane == r) wreg = 1.0f / fmaxf((float)__popcll(b), 1.0f);
    }
    float w_my = __shfl(wreg, tp);                  // my edge's mean weight
    int c4 = lane & 15, grp = lane >> 4;
    const f16* Yb = Y1 + c4 * 4;
    float a0 = 0.f, a1 = 0.f, a2 = 0.f, a3 = 0.f;
    for (int i = 0; i < deg; i += 4) {              // wave-uniform bound
        int idx = i + grp;                          // <= 63 always
        unsigned en = __shfl(my, idx);              // all lanes active
        float we = __shfl(w_my, idx);
        if (idx < deg) {
            f16x4 v = *reinterpret_cast<const f16x4*>(Yb + ((size_t)en << 6));
            a0 += we * (float)v[0]; a1 += we * (float)v[1];
            a2 += we * (float)v[2]; a3 += we * (float)v[3];
        }
    }
    a0 += __shfl_xor(a0, 16); a0 += __shfl_xor(a0, 32);
    a1 += __shfl_xor(a1, 16); a1 += __shfl_xor(a1, 32);
    a2 += __shfl_xor(a2, 16); a2 += __shfl_xor(a2, 32);
    a3 += __shfl_xor(a3, 16); a3 += __shfl_xor(a3, 32);
    if (grp == 0) {
        f16x4 rt = *reinterpret_cast<const f16x4*>(Y1 + ((size_t)n * 17 + 16) * 64 + c4 * 4);
        float4 bb = *reinterpret_cast<const float4*>(b1 + c4 * 4);
        f16x4 o = {(f16)fmaxf(a0 + (float)rt[0] + bb.x, 0.f),
                   (f16)fmaxf(a1 + (float)rt[1] + bb.y, 0.f),
                   (f16)fmaxf(a2 + (float)rt[2] + bb.z, 0.f),
                   (f16)fmaxf(a3 + (float)rt[3] + bb.w, 0.f)};
        *reinterpret_cast<f16x4*>(X1h + (size_t)n * HID + c4 * 4) = o;
    }
}

// ---- fused layer-2 aggregation + finalize ----------------------------------
// wave/node; 16 edge-groups x 4 channel-quads; float4 loads (Y2 f32).
__global__ __launch_bounds__(256)
void k_agg2f(const int* __restrict__ cur, const unsigned* __restrict__ packed,
             const float* __restrict__ Y2, const float* __restrict__ b2,
             float* __restrict__ out) {
    int n = (blockIdx.x * 256 + threadIdx.x) >> 6;
    if (n >= N_NODES) return;
    int lane = threadIdx.x & 63;
    int deg = cur[n]; if (deg > CAP) deg = CAP;
    unsigned my = packed[(size_t)n * CAP + lane];
    int tp = (int)(my % 17u);
    float wreg = 0.f;
#pragma unroll
    for (int r = 0; r < 16; r++) {
        unsigned long long b = __ballot(lane < deg && tp == r);
        if (lane == r) wreg = 1.0f / fmaxf((float)__popcll(b), 1.0f);
    }
    float w_my = __shfl(wreg, tp);
    int c4 = lane & 3, grp = lane >> 2;             // 16 groups x 4 quads
    const float* Yb = Y2 + c4 * 4;
    float a0 = 0.f, a1 = 0.f, a2 = 0.f, a3 = 0.f;
    for (int i = 0; i < deg; i += 16) {             // usually 1-2 iterations
        int idx = i + grp;                          // <= 63 always (i<=48,grp<=15)
        unsigned en = __shfl(my, idx);
        float we = __shfl(w_my, idx);
        if (idx < deg) {
            float4 v = *reinterpret_cast<const float4*>(Yb + ((size_t)en << 4));
            a0 += we * v.x; a1 += we * v.y; a2 += we * v.z; a3 += we * v.w;
        }
    }
#pragma unroll
    for (int sh = 4; sh <= 32; sh <<= 1) {
        a0 += __shfl_xor(a0, sh); a1 += __shfl_xor(a1, sh);
        a2 += __shfl_xor(a2, sh); a3 += __shfl_xor(a3, sh);
    }
    if (grp == 0) {                                 // lanes 0..3
        float4 rt = *reinterpret_cast<const float4*>(Y2 + ((size_t)n * 17 + 16) * 16 + c4 * 4);
        float4 bb = *reinterpret_cast<const float4*>(b2 + c4 * 4);
        float4 o;
        o.x = 1.0f / (1.0f + expf(-(a0 + rt.x + bb.x)));
        o.y = 1.0f / (1.0f + expf(-(a1 + rt.y + bb.y)));
        o.z = 1.0f / (1.0f + expf(-(a2 + rt.z + bb.z)));
        o.w = 1.0f / (1.0f + expf(-(a3 + rt.w + bb.w)));
        *reinterpret_cast<float4*>(out + (size_t)n * NC + c4 * 4) = o;
    }
}

extern "C" void kernel_launch(void* const* d_in, const int* in_sizes, int n_in,
                              void* d_out, int out_size, void* d_ws, size_t ws_size,
                              hipStream_t stream) {
    const float* emb   = (const float*)d_in[0];
    const float* W1    = (const float*)d_in[1];
    const float* root1 = (const float*)d_in[2];
    const float* b1    = (const float*)d_in[3];
    const float* W2    = (const float*)d_in[4];
    const float* root2 = (const float*)d_in[5];
    const float* b2    = (const float*)d_in[6];
    const int*   ei    = (const int*)d_in[7];    // [2, NE]: src then dst
    const int*   et    = (const int*)d_in[8];
    float* out = (float*)d_out;

    char* ws = (char*)d_ws;
    // ws layout (bytes):
    //   cur:      0          .. +200,000      (50000 i32)
    //   Bt1:      200,000    .. +278,528      (1088x128 f16)
    //   Bt2:      478,528    .. +34,816       (272x64 f16)
    //   dctr:     513,344    .. +512          (8 x 16 i32 work-steal counters)
    //   packed:   513,856    .. +12,800,000   (50000x64 u32 buckets)
    //   embh/X1h: 13,313,856 .. +12,800,000   (embh dies at gemm1; X1h aliases)
    //   Y1/Y2:    26,113,856 .. +108,800,000  (Y1 f16 [50000][1088]; Y2 f32 [50000][272])
    int*      cur    = (int*)(ws + 0);
    f16*      Bt1    = (f16*)(ws + 200000);
    f16*      Bt2    = (f16*)(ws + 478528);
    int*      dctr   = (int*)(ws + 513344);
    unsigned* packed = (unsigned*)(ws + 513856);
    f16*      embh   = (f16*)(ws + 13313856);
    f16*      X1h    = (f16*)(ws + 13313856);    // aliases embh (disjoint lifetime)
    f16*      Y1     = (f16*)(ws + 26113856);
    float*    Y2     = (float*)(ws + 26113856);  // aliases Y1 (dead after agg1f)

    hipMemsetAsync(cur, 0, 200000, stream);
    hipMemsetAsync(dctr, 0, 512, stream);

    // pre: scatter(512) + cast(6250) + build_B(613) = 7375 blocks
    k_pre<<<SCT_BLK + CAST_BLK + BB_BLK, 256, 0, stream>>>(
        emb, W1, root1, W2, root2, embh, Bt1, Bt2, ei, et, cur, dctr, packed);

    dim3 g1((J1 + 127) / 128, (N_NODES + 127) / 128);   // 9 x 391
    k_mfma<EMB, f16><<<g1, 512, 0, stream>>>(embh, Bt1, Y1, N_NODES, J1);

    k_agg1f<<<(N_NODES * 64 + 255) / 256, 256, 0, stream>>>(cur, packed, Y1, b1, X1h);

    dim3 g2((J2 + 127) / 128, (N_NODES + 127) / 128);   // 3 x 391
    k_mfma<HID, float><<<g2, 512, 0, stream>>>(X1h, Bt2, Y2, N_NODES, J2);

    k_agg2f<<<(N_NODES * 64 + 255) / 256, 256, 0, stream>>>(cur, packed, Y2, b2, out);
}

// Round 8
// 158.618 us; speedup vs baseline: 1.2918x; 1.2918x over previous
//
#include <hip/hip_runtime.h>
#include <hip/hip_fp16.h>

#define N_NODES 50000
#define EMB 128
#define HID 64
#define NR 16
#define NC 16
#define NE 800000
#define J1 (NR*HID + HID)   /* 1088 = 17*64 */
#define J2 (NR*NC + NC)     /* 272  = 17*16 */
#define CAP 64              /* bucket capacity (deg~Poisson(16)) */
#define CSTR 16             /* cur stride in ints: 1 counter per 64B line */

typedef _Float16 f16;
typedef __attribute__((ext_vector_type(8))) _Float16 f16x8;
typedef __attribute__((ext_vector_type(4))) _Float16 f16x4;
typedef __attribute__((ext_vector_type(4))) float f32x4;

// ---- fused pre-pass: [cast emb->f16 | build Bt1/Bt2] -----------------------
#define PRE_CAST_BLK 6250              /* 1,600,000 f16x4 groups */
#define PRE_BB_BLK 613
__global__ __launch_bounds__(256)
void k_pre(const float* __restrict__ emb, const float* __restrict__ W1,
           const float* __restrict__ root1, const float* __restrict__ W2,
           const float* __restrict__ root2, f16* __restrict__ embh,
           f16* __restrict__ Bt1, f16* __restrict__ Bt2) {
    int bx = blockIdx.x, tid = threadIdx.x;
    if (bx < PRE_CAST_BLK) {
        int i = bx * 256 + tid;
        if (i < N_NODES * EMB / 4) {
            float4 v = reinterpret_cast<const float4*>(emb)[i];
            f16x4 r = {(f16)v.x, (f16)v.y, (f16)v.z, (f16)v.w};
            reinterpret_cast<f16x4*>(embh)[i] = r;
        }
    } else {
        int idx = (bx - PRE_CAST_BLK) * 256 + tid;
        const int total1 = J1 * EMB;   // 139264
        const int total2 = J2 * HID;   // 17408
        if (idx < total1) {
            int j = idx / EMB, i = idx % EMB;
            float v = (j < NR*HID) ? W1[((size_t)(j >> 6) * EMB + i) * HID + (j & 63)]
                                   : root1[i * HID + (j - NR*HID)];
            Bt1[idx] = (f16)v;
        } else if (idx < total1 + total2) {
            int t = idx - total1;
            int j = t / HID, i = t % HID;
            float v = (j < NR*NC) ? W2[((size_t)(j >> 4) * HID + i) * NC + (j & 15)]
                                  : root2[i * NC + (j - NR*NC)];
            Bt2[t] = (f16)v;
        }
    }
}

// ---- hybrid: GEMM1 (Y1 = embh @ Bt1^T) interleaved with edge scatter -------
// 13-block groups: r<9 -> gemm tile; r>=9 -> scatter (2048 edges/group).
// entry = src*17 + type  (Y1 row index / 64). cur padded: 1 counter / line.
__global__ __launch_bounds__(512)
void k_g1s(const f16* __restrict__ A, const f16* __restrict__ Bt,
           f16* __restrict__ C, const int* __restrict__ ei,
           const int* __restrict__ et, int* __restrict__ cur,
           unsigned* __restrict__ packed) {
    constexpr int K = EMB, KP = K + 8;
    __shared__ f16 As[128 * KP];
    __shared__ f16 Bs[128 * KP];
    int g13 = blockIdx.x / 13, r = blockIdx.x % 13;
    int tid = threadIdx.x;

    if (r >= 9) {                       // ---- scatter path ----
        int e = (g13 * 4 + (r - 9)) * 512 + tid;
        if (e < NE) {
            int s = ei[e], d = ei[NE + e], t = et[e];
            int pos = atomicAdd(&cur[(size_t)d * CSTR], 1);
            if (pos < CAP)
                packed[(size_t)d * CAP + pos] = (unsigned)(s * 17 + t);
        }
        return;
    }
    // ---- gemm path: N=N_NODES rows, J=J1 cols ----
    int m0 = g13 * 128, n0 = r * 128;
    constexpr int V = K / 8;
    for (int idx = tid; idx < 128 * V; idx += 512) {
        int rr = idx / V, c = idx % V;
        f16x8 va = {}, vb = {};
        if (m0 + rr < N_NODES) va = *reinterpret_cast<const f16x8*>(A + (size_t)(m0 + rr) * K + c * 8);
        if (n0 + rr < J1)      vb = *reinterpret_cast<const f16x8*>(Bt + (size_t)(n0 + rr) * K + c * 8);
        *reinterpret_cast<f16x8*>(&As[rr * KP + c * 8]) = va;
        *reinterpret_cast<f16x8*>(&Bs[rr * KP + c * 8]) = vb;
    }
    __syncthreads();

    int w = tid >> 6, lane = tid & 63;
    int wr = (w >> 2) * 64, wc = (w & 3) * 32;
    int lr = lane & 15, lk = (lane >> 4) * 8;

    f32x4 acc[4][2];
#pragma unroll
    for (int mm = 0; mm < 4; mm++)
#pragma unroll
        for (int nn = 0; nn < 2; nn++) acc[mm][nn] = (f32x4){0.f, 0.f, 0.f, 0.f};

#pragma unroll
    for (int k0 = 0; k0 < K; k0 += 32) {
        f16x8 a[4], b[2];
#pragma unroll
        for (int mm = 0; mm < 4; mm++)
            a[mm] = *reinterpret_cast<const f16x8*>(&As[(wr + mm*16 + lr) * KP + k0 + lk]);
#pragma unroll
        for (int nn = 0; nn < 2; nn++)
            b[nn] = *reinterpret_cast<const f16x8*>(&Bs[(wc + nn*16 + lr) * KP + k0 + lk]);
#pragma unroll
        for (int mm = 0; mm < 4; mm++)
#pragma unroll
            for (int nn = 0; nn < 2; nn++)
                acc[mm][nn] = __builtin_amdgcn_mfma_f32_16x16x32_f16(a[mm], b[nn], acc[mm][nn], 0, 0, 0);
    }

    int g = lane >> 4;
#pragma unroll
    for (int mm = 0; mm < 4; mm++)
#pragma unroll
        for (int nn = 0; nn < 2; nn++) {
            int col = n0 + wc + nn*16 + lr;
            if (col < J1) {
#pragma unroll
                for (int q = 0; q < 4; q++) {
                    int row = m0 + wr + mm*16 + g*4 + q;
                    if (row < N_NODES) C[(size_t)row * J1 + col] = (f16)acc[mm][nn][q];
                }
            }
        }
}

// ---- MFMA GEMM for layer 2 -------------------------------------------------
template<int K, typename OutT>
__global__ __launch_bounds__(512)
void k_mfma(const f16* __restrict__ A, const f16* __restrict__ Bt,
            OutT* __restrict__ C, int N, int J) {
    constexpr int KP = K + 8;
    __shared__ f16 As[128 * KP];
    __shared__ f16 Bs[128 * KP];
    int tid = threadIdx.x;
    int m0 = blockIdx.y * 128;
    int n0 = blockIdx.x * 128;

    constexpr int V = K / 8;
    for (int idx = tid; idx < 128 * V; idx += 512) {
        int r = idx / V, c = idx % V;
        f16x8 va = {}, vb = {};
        if (m0 + r < N) va = *reinterpret_cast<const f16x8*>(A + (size_t)(m0 + r) * K + c * 8);
        if (n0 + r < J) vb = *reinterpret_cast<const f16x8*>(Bt + (size_t)(n0 + r) * K + c * 8);
        *reinterpret_cast<f16x8*>(&As[r * KP + c * 8]) = va;
        *reinterpret_cast<f16x8*>(&Bs[r * KP + c * 8]) = vb;
    }
    __syncthreads();

    int w = tid >> 6, lane = tid & 63;
    int wr = (w >> 2) * 64, wc = (w & 3) * 32;
    int lr = lane & 15, lk = (lane >> 4) * 8;

    f32x4 acc[4][2];
#pragma unroll
    for (int mm = 0; mm < 4; mm++)
#pragma unroll
        for (int nn = 0; nn < 2; nn++) acc[mm][nn] = (f32x4){0.f, 0.f, 0.f, 0.f};

#pragma unroll
    for (int k0 = 0; k0 < K; k0 += 32) {
        f16x8 a[4], b[2];
#pragma unroll
        for (int mm = 0; mm < 4; mm++)
            a[mm] = *reinterpret_cast<const f16x8*>(&As[(wr + mm*16 + lr) * KP + k0 + lk]);
#pragma unroll
        for (int nn = 0; nn < 2; nn++)
            b[nn] = *reinterpret_cast<const f16x8*>(&Bs[(wc + nn*16 + lr) * KP + k0 + lk]);
#pragma unroll
        for (int mm = 0; mm < 4; mm++)
#pragma unroll
            for (int nn = 0; nn < 2; nn++)
                acc[mm][nn] = __builtin_amdgcn_mfma_f32_16x16x32_f16(a[mm], b[nn], acc[mm][nn], 0, 0, 0);
    }

    int g = lane >> 4;
#pragma unroll
    for (int mm = 0; mm < 4; mm++)
#pragma unroll
        for (int nn = 0; nn < 2; nn++) {
            int col = n0 + wc + nn*16 + lr;
            if (col < J) {
#pragma unroll
                for (int q = 0; q < 4; q++) {
                    int row = m0 + wr + mm*16 + g*4 + q;
                    if (row < N) C[(size_t)row * J + col] = (OutT)acc[mm][nn][q];
                }
            }
        }
}

// ---- fused layer-1 aggregation + finalize ----------------------------------
// wave/node; 4 edge-groups x 16 channel-quads; f16x4 loads; ballot counts.
__global__ __launch_bounds__(256)
void k_agg1f(const int* __restrict__ cur, const unsigned* __restrict__ packed,
             const f16* __restrict__ Y1, const float* __restrict__ b1,
             f16* __restrict__ X1h) {
    int n = (blockIdx.x * 256 + threadIdx.x) >> 6;
    if (n >= N_NODES) return;
    int lane = threadIdx.x & 63;
    int deg = cur[(size_t)n * CSTR]; if (deg > CAP) deg = CAP;
    unsigned my = packed[(size_t)n * CAP + lane];   // stale for lane>=deg, masked
    int tp = (int)(my % 17u);                       // 0..16 always
    float wreg = 0.f;
#pragma unroll
    for (int r = 0; r < 16; r++) {
        unsigned long long b = __ballot(lane < deg && tp == r);
        if (lane == r) wreg = 1.0f / fmaxf((float)__popcll(b), 1.0f);
    }
    float w_my = __shfl(wreg, tp);                  // my edge's mean weight
    int c4 = lane & 15, grp = lane >> 4;
    const f16* Yb = Y1 + c4 * 4;
    float a0 = 0.f, a1 = 0.f, a2 = 0.f, a3 = 0.f;
    for (int i = 0; i < deg; i += 4) {              // wave-uniform bound
        int idx = i + grp;                          // <= 63 always
        unsigned en = __shfl(my, idx);              // all lanes active
        float we = __shfl(w_my, idx);
        if (idx < deg) {
            f16x4 v = *reinterpret_cast<const f16x4*>(Yb + ((size_t)en << 6));
            a0 += we * (float)v[0]; a1 += we * (float)v[1];
            a2 += we * (float)v[2]; a3 += we * (float)v[3];
        }
    }
    a0 += __shfl_xor(a0, 16); a0 += __shfl_xor(a0, 32);
    a1 += __shfl_xor(a1, 16); a1 += __shfl_xor(a1, 32);
    a2 += __shfl_xor(a2, 16); a2 += __shfl_xor(a2, 32);
    a3 += __shfl_xor(a3, 16); a3 += __shfl_xor(a3, 32);
    if (grp == 0) {
        f16x4 rt = *reinterpret_cast<const f16x4*>(Y1 + ((size_t)n * 17 + 16) * 64 + c4 * 4);
        float4 bb = *reinterpret_cast<const float4*>(b1 + c4 * 4);
        f16x4 o = {(f16)fmaxf(a0 + (float)rt[0] + bb.x, 0.f),
                   (f16)fmaxf(a1 + (float)rt[1] + bb.y, 0.f),
                   (f16)fmaxf(a2 + (float)rt[2] + bb.z, 0.f),
                   (f16)fmaxf(a3 + (float)rt[3] + bb.w, 0.f)};
        *reinterpret_cast<f16x4*>(X1h + (size_t)n * HID + c4 * 4) = o;
    }
}

// ---- fused layer-2 aggregation + finalize ----------------------------------
// wave/node; 16 edge-groups x 4 channel-quads; float4 loads (Y2 f32).
__global__ __launch_bounds__(256)
void k_agg2f(const int* __restrict__ cur, const unsigned* __restrict__ packed,
             const float* __restrict__ Y2, const float* __restrict__ b2,
             float* __restrict__ out) {
    int n = (blockIdx.x * 256 + threadIdx.x) >> 6;
    if (n >= N_NODES) return;
    int lane = threadIdx.x & 63;
    int deg = cur[(size_t)n * CSTR]; if (deg > CAP) deg = CAP;
    unsigned my = packed[(size_t)n * CAP + lane];
    int tp = (int)(my % 17u);
    float wreg = 0.f;
#pragma unroll
    for (int r = 0; r < 16; r++) {
        unsigned long long b = __ballot(lane < deg && tp == r);
        if (lane == r) wreg = 1.0f / fmaxf((float)__popcll(b), 1.0f);
    }
    float w_my = __shfl(wreg, tp);
    int c4 = lane & 3, grp = lane >> 2;             // 16 groups x 4 quads
    const float* Yb = Y2 + c4 * 4;
    float a0 = 0.f, a1 = 0.f, a2 = 0.f, a3 = 0.f;
    for (int i = 0; i < deg; i += 16) {             // usually 1-2 iterations
        int idx = i + grp;                          // <= 63 always (i<=48,grp<=15)
        unsigned en = __shfl(my, idx);
        float we = __shfl(w_my, idx);
        if (idx < deg) {
            float4 v = *reinterpret_cast<const float4*>(Yb + ((size_t)en << 4));
            a0 += we * v.x; a1 += we * v.y; a2 += we * v.z; a3 += we * v.w;
        }
    }
#pragma unroll
    for (int sh = 4; sh <= 32; sh <<= 1) {
        a0 += __shfl_xor(a0, sh); a1 += __shfl_xor(a1, sh);
        a2 += __shfl_xor(a2, sh); a3 += __shfl_xor(a3, sh);
    }
    if (grp == 0) {                                 // lanes 0..3
        float4 rt = *reinterpret_cast<const float4*>(Y2 + ((size_t)n * 17 + 16) * 16 + c4 * 4);
        float4 bb = *reinterpret_cast<const float4*>(b2 + c4 * 4);
        float4 o;
        o.x = 1.0f / (1.0f + expf(-(a0 + rt.x + bb.x)));
        o.y = 1.0f / (1.0f + expf(-(a1 + rt.y + bb.y)));
        o.z = 1.0f / (1.0f + expf(-(a2 + rt.z + bb.z)));
        o.w = 1.0f / (1.0f + expf(-(a3 + rt.w + bb.w)));
        *reinterpret_cast<float4*>(out + (size_t)n * NC + c4 * 4) = o;
    }
}

extern "C" void kernel_launch(void* const* d_in, const int* in_sizes, int n_in,
                              void* d_out, int out_size, void* d_ws, size_t ws_size,
                              hipStream_t stream) {
    const float* emb   = (const float*)d_in[0];
    const float* W1    = (const float*)d_in[1];
    const float* root1 = (const float*)d_in[2];
    const float* b1    = (const float*)d_in[3];
    const float* W2    = (const float*)d_in[4];
    const float* root2 = (const float*)d_in[5];
    const float* b2    = (const float*)d_in[6];
    const int*   ei    = (const int*)d_in[7];    // [2, NE]: src then dst
    const int*   et    = (const int*)d_in[8];
    float* out = (float*)d_out;

    char* ws = (char*)d_ws;
    // ws layout (bytes), total 137,913,344:
    //   cur:      0          .. +3,200,000    (50000 x 16 i32 — 1 counter/line)
    //   Bt1:      3,200,000  .. +278,528      (1088x128 f16)
    //   Bt2:      3,478,528  .. +34,816       (272x64 f16)
    //   packed:   3,513,344  .. +12,800,000   (50000x64 u32 buckets)
    //   embh/X1h: 16,313,344 .. +12,800,000   (embh dies at gemm1; X1h aliases)
    //   Y1/Y2:    29,113,344 .. +108,800,000  (Y1 f16 [50000][1088]; Y2 f32 [50000][272])
    int*      cur    = (int*)(ws + 0);
    f16*      Bt1    = (f16*)(ws + 3200000);
    f16*      Bt2    = (f16*)(ws + 3478528);
    unsigned* packed = (unsigned*)(ws + 3513344);
    f16*      embh   = (f16*)(ws + 16313344);
    f16*      X1h    = (f16*)(ws + 16313344);    // aliases embh (disjoint lifetime)
    f16*      Y1     = (f16*)(ws + 29113344);
    float*    Y2     = (float*)(ws + 29113344);  // aliases Y1 (dead after agg1f)

    hipMemsetAsync(cur, 0, 3200000, stream);

    // pre: cast(6250) + build_B(613) = 6863 blocks
    k_pre<<<PRE_CAST_BLK + PRE_BB_BLK, 256, 0, stream>>>(
        emb, W1, root1, W2, root2, embh, Bt1, Bt2);

    // hybrid gemm1+scatter: 391 groups x 13 = 5083 blocks (9 gemm + 4 scatter each)
    k_g1s<<<391 * 13, 512, 0, stream>>>(embh, Bt1, Y1, ei, et, cur, packed);

    k_agg1f<<<(N_NODES * 64 + 255) / 256, 256, 0, stream>>>(cur, packed, Y1, b1, X1h);

    dim3 g2((J2 + 127) / 128, (N_NODES + 127) / 128);   // 3 x 391
    k_mfma<HID, float><<<g2, 512, 0, stream>>>(X1h, Bt2, Y2, N_NODES, J2);

    k_agg2f<<<(N_NODES * 64 + 255) / 256, 256, 0, stream>>>(cur, packed, Y2, b2, out);
}